// Round 8
// baseline (286.075 us; speedup 1.0000x reference)
//
#include <hip/hip_runtime.h>
#include <hip/hip_bf16.h>
#include <math.h>

#define N_   16
#define CIN  16
#define D_   32
#define H_   64
#define W_   64

#define DHW_ (D_ * H_ * W_)
#define HW_  (H_ * W_)

using frag  = __attribute__((ext_vector_type(8))) short;   // 8 bf16 = 4 VGPRs
using v16f  = __attribute__((ext_vector_type(16))) float;  // MFMA 32x32 accum

static __device__ __forceinline__ unsigned short f2bf(float f) {
  union { float f; unsigned u; } a; a.f = f;
  unsigned u = a.u;
  unsigned r = (u + 0x7fffu + ((u >> 16) & 1u)) >> 16;   // RNE
  return (unsigned short)r;
}
static __device__ __forceinline__ unsigned pack2(float lo, float hi) {
  return (unsigned)f2bf(lo) | ((unsigned)f2bf(hi) << 16);
}

// ---- Pass 1: x[n][ic][d][h][w] fp32 -> xT[n][d][h][w][ic] bf16 (LDS-tiled) ---
// Tile = (n, d, 4 h-rows): 16 ic x 4 h x 64 w. Loads float4 (coalesced),
// LDS transpose (pad-20 rows), stores fully dense 1 KiB/wave uint4.
// Block 0 additionally converts weights fp32 [oc][ic][tap] -> bf16 [tap][oc][ic].
__global__ __launch_bounds__(256)
void transpose_x(const float* __restrict__ x, const float* __restrict__ w,
                 __hip_bfloat16* __restrict__ xT, __hip_bfloat16* __restrict__ wT) {
  __shared__ __hip_bfloat16 tile[4 * 64 * 20];   // 10240 B
  const int tid = threadIdx.x;
  const int b = blockIdx.x;
  const int hc = b & 15, d = (b >> 4) & 31, n = b >> 9;
  const int h0 = hc * 4;
  const int wv = tid & 15, icp = (tid >> 4) & 7, hhH = tid >> 7;

  float L[2][2][4];   // [i: ic in pair][j: hh in pair][w 4]
  #pragma unroll
  for (int i = 0; i < 2; ++i)
    #pragma unroll
    for (int j = 0; j < 2; ++j) {
      int ic = 2 * icp + i, hh = 2 * hhH + j;
      const float4 v = *(const float4*)(
          x + (((size_t)(n * CIN + ic) * D_ + d) * H_ + (h0 + hh)) * W_ + 4 * wv);
      L[i][j][0] = v.x; L[i][j][1] = v.y; L[i][j][2] = v.z; L[i][j][3] = v.w;
    }
  #pragma unroll
  for (int j = 0; j < 2; ++j) {
    int hh = 2 * hhH + j;
    #pragma unroll
    for (int k = 0; k < 4; ++k) {
      int ww = 4 * wv + k;
      // adjacent-ic pair packed: one b32 write, ~2-way banks
      *(unsigned*)((char*)tile + ((hh * 64 + ww) * 20 + 2 * icp) * 2) =
          pack2(L[0][j][k], L[1][j][k]);
    }
  }
  __syncthreads();
  #pragma unroll
  for (int kk = 0; kk < 2; ++kk) {
    int task = tid + 256 * kk;
    int icH = task & 1, ww = (task >> 1) & 63, hh = task >> 7;
    const char* src = (const char*)tile + ((hh * 64 + ww) * 20 + 8 * icH) * 2;
    uint2 lo = *(const uint2*)src;
    uint2 hi = *(const uint2*)(src + 8);
    uint4 val = {lo.x, lo.y, hi.x, hi.y};
    *(uint4*)(xT + ((((size_t)(n * D_ + d) * H_ + (h0 + hh)) * W_) + ww) * CIN +
              8 * icH) = val;
  }
  if (b == 0) {
    for (int i = tid; i < 27 * 32 * 16; i += 256) {
      int ic = i & 15, t2 = i >> 4, oc = t2 & 31, tap = t2 >> 5;
      wT[i] = __hip_bfloat16(__hip_bfloat16_raw{f2bf(w[(oc * 16 + ic) * 27 + tap])});
    }
  }
}

// ---- Pass 2: barrier-free, LDS-free MFMA conv + pool + LSE + relu ------------
// One block (4 waves) per (wt+2*hpt, dp, n); wave q -> pooled-h hp = 4*hpt+q.
// A-frags and B-frags loaded DIRECTLY from global (xT coalesced 1 KiB/frag;
// wT 27 KiB, L1-resident). No __shared__, no __syncthreads: loads overlap
// MFMAs via compiler vmcnt scheduling + free wave drift.
__global__ __launch_bounds__(256, 2)
void conv_direct(const __hip_bfloat16* __restrict__ xT,
                 const __hip_bfloat16* __restrict__ wT,
                 const float* __restrict__ bias,
                 float* __restrict__ out) {
  const int tid = threadIdx.x;
  const int lane = tid & 63;
  const int q = tid >> 6;
  const int m = lane & 31;
  const int hs = lane >> 5;
  const int wt = blockIdx.x & 1;
  const int hpt = blockIdx.x >> 1;   // 0..7
  const int dp = blockIdx.y;         // 0..15
  const int n = blockIdx.z;          // 0..15

  const int hp = hpt * 4 + q;        // 0..31
  const float bv = bias[m];
  const int w0 = wt * 32 - 1;
  const int laneoff = m * 16 + hs * 8;
  // w-halo: only (wt==0,kw==0,m==0) and (wt==1,kw==2,m==31) are OOB
  const int edgekw = (wt == 0) ? 0 : 2;
  const bool lane_edge = (wt == 0) ? (m == 0) : (m == 31);

  v16f acc[2][2];
  #pragma unroll
  for (int td = 0; td < 2; ++td)
    #pragma unroll
    for (int th = 0; th < 2; ++th)
      #pragma unroll
      for (int e = 0; e < 16; ++e) acc[td][th][e] = 0.f;

  #pragma unroll
  for (int kw = 0; kw < 3; ++kw) {
    frag a[4][4];   // [plane j = kd+td][row r = kh+th]
    #pragma unroll
    for (int j = 0; j < 4; ++j) {
      const int g = 2 * dp - 1 + j;
      const bool gok = (unsigned)g < (unsigned)D_;
      #pragma unroll
      for (int r = 0; r < 4; ++r) {
        const int h = 2 * hp - 1 + r;
        const bool ok = gok && ((unsigned)h < (unsigned)H_);
        frag t;
        #pragma unroll
        for (int e = 0; e < 8; ++e) t[e] = 0;
        if (ok) {   // wave-uniform branch
          int idx = (((n * D_ + g) * H_ + h) * W_ + (w0 + kw)) * CIN + laneoff;
          idx = idx < 0 ? 0 : idx;   // lane m==0 edge would underflow buffer
          t = *(const frag*)(xT + idx);
          if (kw == edgekw) {        // uniform; per-lane cndmask inside
            #pragma unroll
            for (int e = 0; e < 8; ++e) t[e] = lane_edge ? (short)0 : t[e];
          }
        }
        a[j][r] = t;
      }
    }
    #pragma unroll
    for (int kd = 0; kd < 3; ++kd)
      #pragma unroll
      for (int kh = 0; kh < 3; ++kh) {
        frag bfr = *(const frag*)(wT + ((kd * 3 + kh) * 3 + kw) * 512 + laneoff);
        #pragma unroll
        for (int td = 0; td < 2; ++td)
          #pragma unroll
          for (int th = 0; th < 2; ++th)
            acc[td][th] = __builtin_amdgcn_mfma_f32_32x32x16_bf16(
                a[kd + td][kh + th], bfr, acc[td][th], 0, 0, 0);
      }
  }

  // ---- pool (2x2x2) + bias + LSE over oc + relu + store ----------------------
  #pragma unroll
  for (int j = 0; j < 8; ++j) {
    float p0 = fmaxf(fmaxf(acc[0][0][2 * j], acc[0][0][2 * j + 1]),
                     fmaxf(acc[0][1][2 * j], acc[0][1][2 * j + 1]));
    float p1 = fmaxf(fmaxf(acc[1][0][2 * j], acc[1][0][2 * j + 1]),
                     fmaxf(acc[1][1][2 * j], acc[1][1][2 * j + 1]));
    float v = fmaxf(p0, p1) + bv;
    float M = v;
    #pragma unroll
    for (int s = 16; s >= 1; s >>= 1) M = fmaxf(M, __shfl_xor(M, s, 64));
    float S = __expf(v - M);
    #pragma unroll
    for (int s = 16; s >= 1; s >>= 1) S += __shfl_xor(S, s, 64);
    if (m == 0) {
      float r = fmaxf(M + __logf(S), 0.f);
      int pw = 16 * wt + (j & 1) + 4 * (j >> 1) + 2 * hs;
      out[((n * 16 + dp) * 32 + hp) * 32 + pw] = r;
    }
  }
}

// ---- Fallback (fp32 direct, known-correct) -----------------------------------
__global__ __launch_bounds__(256, 2)
void fused_conv_pool_lse(const float* __restrict__ x,
                         const float* __restrict__ w,
                         const float* __restrict__ bias,
                         float* __restrict__ out) {
  __shared__ float wl[32 * CIN * 27];
  __shared__ float pl[CIN * 4 * 4 * 18];
  const int tx = threadIdx.x;
  const int oc = tx & 31, wq = tx >> 5;
  const int wtile = blockIdx.x, hp = blockIdx.y, n = blockIdx.z;
  for (int i = tx; i < 32 * CIN * 27; i += 256) {
    int o = i / 432, ick = i - o * 432;
    wl[ick * 32 + o] = w[i];
  }
  const float bv = bias[oc];
  const int h0 = 2 * hp - 1, w0 = 16 * wtile - 1, pwoff = 2 * wq;
  for (int dp = 0; dp < 16; ++dp) {
    const int d0 = 2 * dp - 1;
    __syncthreads();
    for (int i = tx; i < CIN * 4 * 4 * 18; i += 256) {
      int ww = i % 18, t = i / 18;
      int h = t & 3; t >>= 2;
      int d = t & 3, ic = t >> 2;
      int gd = d0 + d, gh = h0 + h, gw = w0 + ww;
      float v = 0.f;
      if ((unsigned)gd < (unsigned)D_ && (unsigned)gh < (unsigned)H_ &&
          (unsigned)gw < (unsigned)W_)
        v = x[(((n * CIN + ic) * D_ + gd) * H_ + gh) * W_ + gw];
      pl[i] = v;
    }
    __syncthreads();
    float acc[2][2][2] = {};
    for (int ic = 0; ic < CIN; ++ic) {
      float rv[4][4][4];
      const float* pb = &pl[ic * 288 + pwoff];
      #pragma unroll
      for (int d = 0; d < 4; ++d)
        #pragma unroll
        for (int h = 0; h < 4; ++h) {
          const float2* p2 = (const float2*)(pb + (d * 4 + h) * 18);
          float2 a = p2[0], b2 = p2[1];
          rv[d][h][0] = a.x; rv[d][h][1] = a.y;
          rv[d][h][2] = b2.x; rv[d][h][3] = b2.y;
        }
      const float* wb = &wl[ic * 27 * 32 + oc];
      #pragma unroll
      for (int kd = 0; kd < 3; ++kd)
        #pragma unroll
        for (int kh = 0; kh < 3; ++kh)
          #pragma unroll
          for (int kw = 0; kw < 3; ++kw) {
            float wv = wb[((kd * 3 + kh) * 3 + kw) * 32];
            #pragma unroll
            for (int pd = 0; pd < 2; ++pd)
              #pragma unroll
              for (int ph = 0; ph < 2; ++ph)
                #pragma unroll
                for (int pw = 0; pw < 2; ++pw)
                  acc[pd][ph][pw] = fmaf(wv, rv[pd + kd][ph + kh][pw + kw], acc[pd][ph][pw]);
          }
    }
    float mx = acc[0][0][0];
    mx = fmaxf(mx, acc[0][0][1]); mx = fmaxf(mx, acc[0][1][0]);
    mx = fmaxf(mx, acc[0][1][1]); mx = fmaxf(mx, acc[1][0][0]);
    mx = fmaxf(mx, acc[1][0][1]); mx = fmaxf(mx, acc[1][1][0]);
    mx = fmaxf(mx, acc[1][1][1]);
    float v = mx + bv;
    float M = v;
    #pragma unroll
    for (int s = 16; s >= 1; s >>= 1) M = fmaxf(M, __shfl_xor(M, s, 64));
    float S = __expf(v - M);
    #pragma unroll
    for (int s = 16; s >= 1; s >>= 1) S += __shfl_xor(S, s, 64);
    if (oc == 0) {
      float r = M + __logf(S);
      out[((n * 16 + dp) * 32 + hp) * 32 + wtile * 8 + wq] = fmaxf(r, 0.f);
    }
  }
}

extern "C" void kernel_launch(void* const* d_in, const int* in_sizes, int n_in,
                              void* d_out, int out_size, void* d_ws, size_t ws_size,
                              hipStream_t stream) {
  const float* x = (const float*)d_in[0];
  const float* w = (const float*)d_in[1];
  const float* b = (const float*)d_in[2];
  float* out = (float*)d_out;
  const size_t nxT = (size_t)N_ * D_ * H_ * W_ * CIN * 2;   // 64 MiB
  const size_t need = nxT + (size_t)27 * 32 * 16 * 2;       // + 27 KiB
  if (ws_size >= need) {
    __hip_bfloat16* xT = (__hip_bfloat16*)d_ws;
    __hip_bfloat16* wT = (__hip_bfloat16*)((char*)d_ws + nxT);
    transpose_x<<<dim3(8192), dim3(256), 0, stream>>>(x, w, xT, wT);
    conv_direct<<<dim3(16, 16, 16), dim3(256), 0, stream>>>(xT, wT, b, out);
  } else {
    fused_conv_pool_lse<<<dim3(4, 32, 16), dim3(256), 0, stream>>>(x, w, b, out);
  }
}